// Round 1
// baseline (599.139 us; speedup 1.0000x reference)
//
#include <hip/hip_runtime.h>
#include <hip/hip_bf16.h>

#define HIDDEN 512
#define IMGF   2048
#define RNDS   10

typedef float  f32x4  __attribute__((ext_vector_type(4)));
typedef __bf16 bf16x8 __attribute__((ext_vector_type(8)));
typedef unsigned short u16x8 __attribute__((ext_vector_type(8)));

__device__ __forceinline__ unsigned short f2bf(float x) {
    union { float f; unsigned u; } v; v.f = x;
    unsigned r = v.u + 0x7FFFu + ((v.u >> 16) & 1u);   // RNE
    return (unsigned short)(r >> 16);
}

#define BM 128
#define BN 128
#define BK 32
#define LDP 40   // padded LDS row stride (halfwords); 80 B, 16B-aligned, 2-way max conflict

// out[m][n] = tanh( sum_k A[m][k] * W[n][k] + bias[n] )  (+ resid[m][n])
// A[m][k] = (k < kSplit) ? A0[m*lda0 + k] : A1[m*lda1 + k - kSplit]
template<bool RESID>
__global__ __launch_bounds__(256, 2)
void gemm_bt_tanh(const float* __restrict__ A0, int lda0,
                  const float* __restrict__ A1, int lda1, int kSplit,
                  const float* __restrict__ W,
                  const float* __restrict__ bias,
                  const float* __restrict__ resid,
                  float* __restrict__ out, int N, int K)
{
    __shared__ unsigned short lA[BM * LDP];
    __shared__ unsigned short lB[BN * LDP];
    const int bm = blockIdx.x * BM;
    const int bn = blockIdx.y * BN;
    const int t    = threadIdx.x;
    const int lane = t & 63;
    const int wave = t >> 6;
    const int wm = (wave & 1) * 64;
    const int wn = (wave >> 1) * 64;
    const int lr = lane & 15;   // row-in-16 for A/B frag
    const int lq = lane >> 4;   // quad

    const int srow = t >> 3;    // staging row 0..31 (+32*i)
    const int skq  = t & 7;     // float4 index within 32-elem row

    f32x4 acc[4][4] = {};

    for (int k0 = 0; k0 < K; k0 += BK) {
        const float* Ab; int lda;
        if (k0 < kSplit) { Ab = A0 + (size_t)bm * lda0 + k0;            lda = lda0; }
        else             { Ab = A1 + (size_t)bm * lda1 + (k0 - kSplit); lda = lda1; }
        const float* Wb = W + (size_t)bn * K + k0;

        if (k0) __syncthreads();   // previous tile's reads done
        #pragma unroll
        for (int i = 0; i < 4; ++i) {
            const int row = srow + i * 32;
            float4 v = *((const float4*)(Ab + (size_t)row * lda) + skq);
            unsigned lo = (unsigned)f2bf(v.x) | ((unsigned)f2bf(v.y) << 16);
            unsigned hi = (unsigned)f2bf(v.z) | ((unsigned)f2bf(v.w) << 16);
            *(uint2*)&lA[row * LDP + skq * 4] = make_uint2(lo, hi);
            float4 w = *((const float4*)(Wb + (size_t)row * K) + skq);
            lo = (unsigned)f2bf(w.x) | ((unsigned)f2bf(w.y) << 16);
            hi = (unsigned)f2bf(w.z) | ((unsigned)f2bf(w.w) << 16);
            *(uint2*)&lB[row * LDP + skq * 4] = make_uint2(lo, hi);
        }
        __syncthreads();

        bf16x8 af[4], bf[4];
        #pragma unroll
        for (int mi = 0; mi < 4; ++mi)
            af[mi] = __builtin_bit_cast(bf16x8,
                *(const u16x8*)&lA[(wm + mi * 16 + lr) * LDP + lq * 8]);
        #pragma unroll
        for (int ni = 0; ni < 4; ++ni)
            bf[ni] = __builtin_bit_cast(bf16x8,
                *(const u16x8*)&lB[(wn + ni * 16 + lr) * LDP + lq * 8]);
        #pragma unroll
        for (int mi = 0; mi < 4; ++mi)
            #pragma unroll
            for (int ni = 0; ni < 4; ++ni)
                acc[mi][ni] = __builtin_amdgcn_mfma_f32_16x16x32_bf16(
                    af[mi], bf[ni], acc[mi][ni], 0, 0, 0);
    }

    // epilogue: D[m = (lane>>4)*4 + j][n = lane&15]  (verified m89/m91 layout)
    #pragma unroll
    for (int ni = 0; ni < 4; ++ni) {
        const int col = bn + wn + ni * 16 + lr;
        const float bc = bias[col];
        #pragma unroll
        for (int mi = 0; mi < 4; ++mi) {
            const int rbase = bm + wm + mi * 16 + lq * 4;
            #pragma unroll
            for (int j = 0; j < 4; ++j) {
                const int row = rbase + j;
                float v = tanhf(acc[mi][ni][j] + bc);
                if (RESID) v += resid[(size_t)row * N + col];
                out[(size_t)row * N + col] = v;
            }
        }
    }
}

// One block per BR-row: scores -> softmax -> weighted hist sum.
// hist kept in registers between the two passes (single HBM read).
__global__ __launch_bounds__(256)
void attn_embed(const float* __restrict__ hist,
                const float* __restrict__ fused,
                const float* __restrict__ w_att,
                const float* __restrict__ b_att,
                float* __restrict__ hist_embed)
{
    __shared__ float red[RNDS * 4];
    __shared__ float sc[RNDS];
    const int b = blockIdx.x, t = threadIdx.x;
    const int d0 = t, d1 = t + 256;
    const float g0 = fused[(size_t)b * HIDDEN + d0] * w_att[d0];
    const float g1 = fused[(size_t)b * HIDDEN + d1] * w_att[d1];
    const float* hb = hist + (size_t)b * RNDS * HIDDEN;

    float h0[RNDS], h1[RNDS], p[RNDS];
    #pragma unroll
    for (int r = 0; r < RNDS; ++r) {
        h0[r] = hb[r * HIDDEN + d0];
        h1[r] = hb[r * HIDDEN + d1];
        p[r]  = h0[r] * g0 + h1[r] * g1;
    }
    const int lane = t & 63, wv = t >> 6;
    #pragma unroll
    for (int r = 0; r < RNDS; ++r) {
        float v = p[r];
        #pragma unroll
        for (int off = 32; off > 0; off >>= 1) v += __shfl_down(v, off, 64);
        if (lane == 0) red[r * 4 + wv] = v;
    }
    __syncthreads();
    if (t < RNDS)
        sc[t] = red[t * 4] + red[t * 4 + 1] + red[t * 4 + 2] + red[t * 4 + 3] + b_att[0];
    __syncthreads();

    float mx = -1e30f;
    #pragma unroll
    for (int r = 0; r < RNDS; ++r) mx = fmaxf(mx, sc[r]);
    float s = 0.f, a[RNDS];
    #pragma unroll
    for (int r = 0; r < RNDS; ++r) { a[r] = __expf(sc[r] - mx); s += a[r]; }
    const float inv = 1.0f / s;
    float e0 = 0.f, e1 = 0.f;
    #pragma unroll
    for (int r = 0; r < RNDS; ++r) { e0 += a[r] * h0[r]; e1 += a[r] * h1[r]; }
    hist_embed[(size_t)b * HIDDEN + d0] = e0 * inv;
    hist_embed[(size_t)b * HIDDEN + d1] = e1 * inv;
}

extern "C" void kernel_launch(void* const* d_in, const int* in_sizes, int n_in,
                              void* d_out, int out_size, void* d_ws, size_t ws_size,
                              hipStream_t stream)
{
    const float* img    = (const float*)d_in[0];
    const float* ques   = (const float*)d_in[1];
    const float* hist   = (const float*)d_in[2];
    const float* W_fuse = (const float*)d_in[3];
    const float* b_fuse = (const float*)d_in[4];
    const float* w_att  = (const float*)d_in[5];
    const float* b_att  = (const float*)d_in[6];
    const float* W_hist = (const float*)d_in[7];
    const float* b_hist = (const float*)d_in[8];

    const int BR = in_sizes[1] / HIDDEN;   // ques is [BR, 512] -> 5120

    float* fused  = (float*)d_ws;                    // BR*512 fp32
    float* hembed = fused + (size_t)BR * HIDDEN;     // BR*512 fp32
    float* outf   = (float*)d_out;

    dim3 blk(256);
    dim3 g1(BR / BM, HIDDEN / BN);   // 40 x 4

    // fused = tanh(cat(img,ques) @ W_fuse^T + b_fuse)
    gemm_bt_tanh<false><<<g1, blk, 0, stream>>>(
        img, IMGF, ques, HIDDEN, IMGF,
        W_fuse, b_fuse, nullptr, fused, HIDDEN, IMGF + HIDDEN);

    // attention + weighted history sum
    attn_embed<<<dim3(BR), blk, 0, stream>>>(hist, fused, w_att, b_att, hembed);

    // out = fused + tanh(hembed @ W_hist^T + b_hist)
    gemm_bt_tanh<true><<<g1, blk, 0, stream>>>(
        hembed, HIDDEN, nullptr, 0, HIDDEN,
        W_hist, b_hist, fused, outf, HIDDEN, HIDDEN);
}

// Round 2
// 263.210 us; speedup vs baseline: 2.2763x; 2.2763x over previous
//
#include <hip/hip_runtime.h>
#include <hip/hip_bf16.h>

#define HIDDEN 512
#define IMGF   2048
#define RNDS   10

typedef float  f32x4  __attribute__((ext_vector_type(4)));
typedef __bf16 bf16x8 __attribute__((ext_vector_type(8)));
typedef unsigned short u16x8 __attribute__((ext_vector_type(8)));

__device__ __forceinline__ unsigned short f2bf(float x) {
    union { float f; unsigned u; } v; v.f = x;
    unsigned r = v.u + 0x7FFFu + ((v.u >> 16) & 1u);   // RNE
    return (unsigned short)(r >> 16);
}

__device__ __forceinline__ void cp16_async(const void* g, void* l) {
    __builtin_amdgcn_global_load_lds(
        (const __attribute__((address_space(1))) unsigned int*)g,
        (__attribute__((address_space(3))) unsigned int*)l,
        16, 0, 0);
}

// ---------------------------------------------------------------------------
// fp32 -> bf16 pre-convert of img / ques / W_fuse / W_hist (one BW pass)
// ---------------------------------------------------------------------------
__global__ __launch_bounds__(256)
void cvt_bf16(const float* __restrict__ p0, long n0,
              const float* __restrict__ p1, long n1,
              const float* __restrict__ p2, long n2,
              const float* __restrict__ p3, long n3,
              unsigned short* __restrict__ q0, unsigned short* __restrict__ q1,
              unsigned short* __restrict__ q2, unsigned short* __restrict__ q3)
{
    long i = ((long)blockIdx.x * 256 + threadIdx.x) * 4;   // element index
    const float* s; unsigned short* d; long j;
    if      (i < n0)            { s = p0; d = q0; j = i; }
    else if (i < n0 + n1)       { s = p1; d = q1; j = i - n0; }
    else if (i < n0 + n1 + n2)  { s = p2; d = q2; j = i - n0 - n1; }
    else                        { s = p3; d = q3; j = i - n0 - n1 - n2; }
    float4 v = *(const float4*)(s + j);
    ushort4 o;
    o.x = f2bf(v.x); o.y = f2bf(v.y); o.z = f2bf(v.z); o.w = f2bf(v.w);
    *(ushort4*)(d + j) = o;
}

// ---------------------------------------------------------------------------
// 64x64x64 bf16 MFMA GEMM, async global_load_lds staging, double-buffered.
// out[m][n] = tanh(sum_k A[m][k]*W[n][k] + bias[n]) (+ resid[m][n])
// A concat: k < kSplit -> A0, else A1. All A/W pointers are bf16 (u16).
// LDS: tile [64 rows][8 chunks of 16B], chunk col XOR-swizzled by (row&7)
// so ds_read_b128 fragment reads are bank-conflict-free while keeping the
// lane-contiguous LDS destinations global_load_lds requires.
// ---------------------------------------------------------------------------
template<bool RESID>
__global__ __launch_bounds__(256, 2)
void gemm_bt_tanh(const unsigned short* __restrict__ A0, int lda0,
                  const unsigned short* __restrict__ A1, int lda1, int kSplit,
                  const unsigned short* __restrict__ W,
                  const float* __restrict__ bias,
                  const float* __restrict__ resid,
                  float* __restrict__ out, int K)
{
    __shared__ unsigned short lA[2][64 * 64];
    __shared__ unsigned short lB[2][64 * 64];

    const int bm = blockIdx.x * 64;
    const int bn = blockIdx.y * 64;
    const int t    = threadIdx.x;
    const int lane = t & 63;
    const int wave = t >> 6;
    const int wm = (wave & 1) * 32;
    const int wn = (wave >> 1) * 32;
    const int lr = lane & 15;
    const int lq = lane >> 4;

    const unsigned short* Wb0 = W + (size_t)bn * K;

    auto stage64 = [&](const unsigned short* G, int lda, unsigned short* L) {
        #pragma unroll
        for (int h = 0; h < 2; ++h) {
            int ci = h * 256 + t;           // 16B chunk 0..511
            int r  = ci >> 3;               // tile row 0..63
            int s  = (ci & 7) ^ (r & 7);    // swizzled k-chunk
            cp16_async(G + (size_t)r * lda + s * 8, L + ci * 8);
        }
    };
    auto stage_tiles = [&](int kt, int buf) {
        int k0 = kt << 6;
        const unsigned short* Ab; int lda;
        if (k0 < kSplit) { Ab = A0 + (size_t)bm * lda0 + k0;            lda = lda0; }
        else             { Ab = A1 + (size_t)bm * lda1 + (k0 - kSplit); lda = lda1; }
        stage64(Ab, lda, &lA[buf][0]);
        stage64(Wb0 + k0, K, &lB[buf][0]);
    };

    f32x4 acc[2][2] = {};
    const int NT = K >> 6;

    stage_tiles(0, 0);
    for (int kt = 0; kt < NT; ++kt) {
        __syncthreads();                    // drains tile-kt loads (vmcnt)
        if (kt + 1 < NT) stage_tiles(kt + 1, (kt + 1) & 1);   // async prefetch
        const unsigned short* a = &lA[kt & 1][0];
        const unsigned short* b = &lB[kt & 1][0];
        #pragma unroll
        for (int kh = 0; kh < 2; ++kh) {
            bf16x8 af[2], bfr[2];
            #pragma unroll
            for (int mi = 0; mi < 2; ++mi) {
                int r = wm + mi * 16 + lr, c = kh * 4 + lq;
                af[mi] = __builtin_bit_cast(bf16x8,
                    *(const u16x8*)&a[r * 64 + ((c ^ (r & 7)) * 8)]);
            }
            #pragma unroll
            for (int ni = 0; ni < 2; ++ni) {
                int r = wn + ni * 16 + lr, c = kh * 4 + lq;
                bfr[ni] = __builtin_bit_cast(bf16x8,
                    *(const u16x8*)&b[r * 64 + ((c ^ (r & 7)) * 8)]);
            }
            #pragma unroll
            for (int mi = 0; mi < 2; ++mi)
                #pragma unroll
                for (int ni = 0; ni < 2; ++ni)
                    acc[mi][ni] = __builtin_amdgcn_mfma_f32_16x16x32_bf16(
                        af[mi], bfr[ni], acc[mi][ni], 0, 0, 0);
        }
    }

    // epilogue: D[m = lq*4 + j][n = lr]  (verified m89/m91 layout)
    #pragma unroll
    for (int ni = 0; ni < 2; ++ni) {
        const int col = bn + wn + ni * 16 + lr;
        const float bc = bias[col];
        #pragma unroll
        for (int mi = 0; mi < 2; ++mi) {
            const int rbase = bm + wm + mi * 16 + lq * 4;
            #pragma unroll
            for (int j = 0; j < 4; ++j) {
                const int row = rbase + j;
                float v = tanhf(acc[mi][ni][j] + bc);
                if (RESID) v += resid[(size_t)row * HIDDEN + col];
                out[(size_t)row * HIDDEN + col] = v;
            }
        }
    }
}

// ---------------------------------------------------------------------------
// Attention: one wave per BR-row, lane holds 8 dims x 10 rounds in registers.
// No LDS, no barriers. Writes hist_embed directly as bf16 (GEMM2's A).
// ---------------------------------------------------------------------------
__global__ __launch_bounds__(256)
void attn_embed(const float* __restrict__ hist,
                const float* __restrict__ fused,
                const float* __restrict__ w_att,
                const float* __restrict__ b_att,
                unsigned short* __restrict__ hembed)
{
    const int lane = threadIdx.x & 63;
    const int wave = threadIdx.x >> 6;
    const int b = blockIdx.x * 4 + wave;
    const int d = lane * 8;

    float g[8];
    {
        const float4 f0 = *(const float4*)(fused + (size_t)b * HIDDEN + d);
        const float4 f1 = *(const float4*)(fused + (size_t)b * HIDDEN + d + 4);
        const float4 w0 = *(const float4*)(w_att + d);
        const float4 w1 = *(const float4*)(w_att + d + 4);
        g[0]=f0.x*w0.x; g[1]=f0.y*w0.y; g[2]=f0.z*w0.z; g[3]=f0.w*w0.w;
        g[4]=f1.x*w1.x; g[5]=f1.y*w1.y; g[6]=f1.z*w1.z; g[7]=f1.w*w1.w;
    }
    const float* hb = hist + (size_t)b * RNDS * HIDDEN + d;

    float h[RNDS][8], p[RNDS];
    #pragma unroll
    for (int r = 0; r < RNDS; ++r) {
        const float4 a0 = *(const float4*)(hb + r * HIDDEN);
        const float4 a1 = *(const float4*)(hb + r * HIDDEN + 4);
        h[r][0]=a0.x; h[r][1]=a0.y; h[r][2]=a0.z; h[r][3]=a0.w;
        h[r][4]=a1.x; h[r][5]=a1.y; h[r][6]=a1.z; h[r][7]=a1.w;
        float s = 0.f;
        #pragma unroll
        for (int i = 0; i < 8; ++i) s += h[r][i] * g[i];
        p[r] = s;
    }
    #pragma unroll
    for (int r = 0; r < RNDS; ++r)
        #pragma unroll
        for (int m = 1; m < 64; m <<= 1)
            p[r] += __shfl_xor(p[r], m, 64);

    const float ba = b_att[0];
    float mx = -1e30f;
    #pragma unroll
    for (int r = 0; r < RNDS; ++r) mx = fmaxf(mx, p[r] + ba);
    float sum = 0.f, a[RNDS];
    #pragma unroll
    for (int r = 0; r < RNDS; ++r) { a[r] = __expf(p[r] + ba - mx); sum += a[r]; }
    const float inv = 1.0f / sum;

    float e[8] = {};
    #pragma unroll
    for (int r = 0; r < RNDS; ++r)
        #pragma unroll
        for (int i = 0; i < 8; ++i) e[i] += a[r] * h[r][i];

    ushort4 o0, o1;
    o0.x=f2bf(e[0]*inv); o0.y=f2bf(e[1]*inv); o0.z=f2bf(e[2]*inv); o0.w=f2bf(e[3]*inv);
    o1.x=f2bf(e[4]*inv); o1.y=f2bf(e[5]*inv); o1.z=f2bf(e[6]*inv); o1.w=f2bf(e[7]*inv);
    unsigned short* q = hembed + (size_t)b * HIDDEN + d;
    *(ushort4*)q = o0;
    *(ushort4*)(q + 4) = o1;
}

extern "C" void kernel_launch(void* const* d_in, const int* in_sizes, int n_in,
                              void* d_out, int out_size, void* d_ws, size_t ws_size,
                              hipStream_t stream)
{
    const float* img    = (const float*)d_in[0];
    const float* ques   = (const float*)d_in[1];
    const float* hist   = (const float*)d_in[2];
    const float* W_fuse = (const float*)d_in[3];
    const float* b_fuse = (const float*)d_in[4];
    const float* w_att  = (const float*)d_in[5];
    const float* b_att  = (const float*)d_in[6];
    const float* W_hist = (const float*)d_in[7];
    const float* b_hist = (const float*)d_in[8];

    const long n_img  = in_sizes[0];
    const long n_ques = in_sizes[1];
    const long n_Wf   = in_sizes[3];
    const long n_Wh   = in_sizes[7];
    const int  BR     = (int)(n_ques / HIDDEN);   // 5120

    unsigned short* imgb  = (unsigned short*)d_ws;
    unsigned short* quesb = imgb  + n_img;
    unsigned short* Wfb   = quesb + n_ques;
    unsigned short* Whb   = Wfb   + n_Wf;
    unsigned short* hembb = Whb   + n_Wh;         // BR*512 bf16
    float* fused = (float*)d_out;                 // fused lives in d_out

    // 1) fp32 -> bf16 conversions (img, ques, W_fuse, W_hist)
    const long total4 = (n_img + n_ques + n_Wf + n_Wh) / 4;
    cvt_bf16<<<dim3((unsigned)((total4 + 255) / 256)), dim3(256), 0, stream>>>(
        img, n_img, ques, n_ques, W_fuse, n_Wf, W_hist, n_Wh,
        imgb, quesb, Wfb, Whb);

    dim3 blk(256);
    dim3 g1(BR / 64, HIDDEN / 64);   // 80 x 8 = 640 blocks

    // 2) fused = tanh(cat(img,ques) @ W_fuse^T + b_fuse)   -> d_out
    gemm_bt_tanh<false><<<g1, blk, 0, stream>>>(
        imgb, IMGF, quesb, HIDDEN, IMGF,
        Wfb, b_fuse, nullptr, fused, IMGF + HIDDEN);

    // 3) attention + weighted history sum -> hembb (bf16)
    attn_embed<<<dim3(BR / 4), blk, 0, stream>>>(hist, fused, w_att, b_att, hembb);

    // 4) out = fused + tanh(hembb @ W_hist^T + b_hist)  (in-place over d_out)
    gemm_bt_tanh<true><<<g1, blk, 0, stream>>>(
        hembb, HIDDEN, nullptr, 0, HIDDEN,
        Whb, b_hist, fused, (float*)d_out, HIDDEN);
}

// Round 3
// 256.989 us; speedup vs baseline: 2.3314x; 1.0242x over previous
//
#include <hip/hip_runtime.h>
#include <hip/hip_bf16.h>

#define HIDDEN 512
#define IMGF   2048
#define RNDS   10

typedef float  f32x4  __attribute__((ext_vector_type(4)));
typedef __bf16 bf16x8 __attribute__((ext_vector_type(8)));
typedef unsigned short u16x8 __attribute__((ext_vector_type(8)));

__device__ __forceinline__ unsigned short f2bf(float x) {
    union { float f; unsigned u; } v; v.f = x;
    unsigned r = v.u + 0x7FFFu + ((v.u >> 16) & 1u);   // RNE
    return (unsigned short)(r >> 16);
}
__device__ __forceinline__ float bf2f(unsigned short h) {
    union { unsigned u; float f; } v; v.u = ((unsigned)h) << 16;
    return v.f;
}

__device__ __forceinline__ void cp16_async(const void* g, void* l) {
    __builtin_amdgcn_global_load_lds(
        (const __attribute__((address_space(1))) unsigned int*)g,
        (__attribute__((address_space(3))) unsigned int*)l,
        16, 0, 0);
}

// ---------------------------------------------------------------------------
// fp32 -> bf16 pre-convert of img / ques / W_fuse / W_hist (one BW pass)
// ---------------------------------------------------------------------------
__global__ __launch_bounds__(256)
void cvt_bf16(const float* __restrict__ p0, long n0,
              const float* __restrict__ p1, long n1,
              const float* __restrict__ p2, long n2,
              const float* __restrict__ p3, long n3,
              unsigned short* __restrict__ q0, unsigned short* __restrict__ q1,
              unsigned short* __restrict__ q2, unsigned short* __restrict__ q3)
{
    long i = ((long)blockIdx.x * 256 + threadIdx.x) * 4;
    const float* s; unsigned short* d; long j;
    if      (i < n0)            { s = p0; d = q0; j = i; }
    else if (i < n0 + n1)       { s = p1; d = q1; j = i - n0; }
    else if (i < n0 + n1 + n2)  { s = p2; d = q2; j = i - n0 - n1; }
    else                        { s = p3; d = q3; j = i - n0 - n1 - n2; }
    float4 v = *(const float4*)(s + j);
    ushort4 o;
    o.x = f2bf(v.x); o.y = f2bf(v.y); o.z = f2bf(v.z); o.w = f2bf(v.w);
    *(ushort4*)(d + j) = o;
}

// ---------------------------------------------------------------------------
// 32x64x64 bf16 MFMA GEMM, async global_load_lds staging, double-buffered.
// Small tile -> 1280 blocks (~5/CU resident, ~20 waves/CU) so K-step load
// latency is hidden by TLP instead of (compiler-defeated) pipelining.
// out[m][n] = tanh(sum_k A[m][k]*W[n][k] + bias[n]) (+ resid[m][n])
// RESID=false: write bf16 to outb.  RESID=true: out fp32 += bf16 resid.
// LDS chunk-col XOR-swizzled by (row&7): conflict-free ds_read_b128 while
// keeping the lane-contiguous LDS destinations global_load_lds requires.
// ---------------------------------------------------------------------------
template<bool RESID>
__global__ __launch_bounds__(256, 4)
void gemm_bt_tanh(const unsigned short* __restrict__ A0, int lda0,
                  const unsigned short* __restrict__ A1, int lda1, int kSplit,
                  const unsigned short* __restrict__ W,
                  const float* __restrict__ bias,
                  const unsigned short* __restrict__ residb,
                  float* __restrict__ outf, unsigned short* __restrict__ outb,
                  int K)
{
    __shared__ unsigned short lA[2][32 * 64];
    __shared__ unsigned short lB[2][64 * 64];

    const int bm = blockIdx.x * 32;
    const int bn = blockIdx.y * 64;
    const int t    = threadIdx.x;
    const int lane = t & 63;
    const int wave = t >> 6;
    const int wm = (wave >> 1) * 16;   // 0 / 16
    const int wn = (wave & 1) * 32;    // 0 / 32
    const int lr = lane & 15;
    const int lq = lane >> 4;

    const unsigned short* Wb0 = W + (size_t)bn * K;

    auto stage_tiles = [&](int kt, int buf) {
        int k0 = kt << 6;
        const unsigned short* Ab; int lda;
        if (k0 < kSplit) { Ab = A0 + (size_t)bm * lda0 + k0;            lda = lda0; }
        else             { Ab = A1 + (size_t)bm * lda1 + (k0 - kSplit); lda = lda1; }
        {   // A: 32x64 = 256 chunks of 16B, one per thread
            int r = t >> 3, s = (t & 7) ^ (r & 7);
            cp16_async(Ab + (size_t)r * lda + s * 8, &lA[buf][t * 8]);
        }
        #pragma unroll
        for (int h = 0; h < 2; ++h) {   // B: 64x64 = 512 chunks
            int ci = h * 256 + t;
            int r = ci >> 3, s = (ci & 7) ^ (r & 7);
            cp16_async(Wb0 + k0 + (size_t)r * K + s * 8, &lB[buf][ci * 8]);
        }
    };

    f32x4 acc[2] = {};
    const int NT = K >> 6;

    stage_tiles(0, 0);
    for (int kt = 0; kt < NT; ++kt) {
        __syncthreads();                                   // drains tile-kt loads
        if (kt + 1 < NT) stage_tiles(kt + 1, (kt + 1) & 1); // async prefetch
        const unsigned short* a = &lA[kt & 1][0];
        const unsigned short* b = &lB[kt & 1][0];
        #pragma unroll
        for (int kh = 0; kh < 2; ++kh) {
            const int c = kh * 4 + lq;
            const int ra = wm + lr;
            bf16x8 af = __builtin_bit_cast(bf16x8,
                *(const u16x8*)&a[ra * 64 + ((c ^ (ra & 7)) * 8)]);
            #pragma unroll
            for (int ni = 0; ni < 2; ++ni) {
                const int rb = wn + ni * 16 + lr;
                bf16x8 bf = __builtin_bit_cast(bf16x8,
                    *(const u16x8*)&b[rb * 64 + ((c ^ (rb & 7)) * 8)]);
                acc[ni] = __builtin_amdgcn_mfma_f32_16x16x32_bf16(
                    af, bf, acc[ni], 0, 0, 0);
            }
        }
    }

    // epilogue: D[m = lq*4 + j][n = lr]  (verified m89/m91 layout)
    #pragma unroll
    for (int ni = 0; ni < 2; ++ni) {
        const int col = bn + wn + ni * 16 + lr;
        const float bc = bias[col];
        const int rbase = bm + wm + lq * 4;
        #pragma unroll
        for (int j = 0; j < 4; ++j) {
            const size_t idx = (size_t)(rbase + j) * HIDDEN + col;
            float v = tanhf(acc[ni][j] + bc);
            if (RESID) outf[idx] = v + bf2f(residb[idx]);
            else       outb[idx] = f2bf(v);
        }
    }
}

// ---------------------------------------------------------------------------
// Attention: one wave per BR-row, lane holds 8 dims x 10 rounds in registers.
// No LDS, no barriers. fused is bf16; writes hist_embed as bf16 (GEMM2's A).
// ---------------------------------------------------------------------------
__global__ __launch_bounds__(256)
void attn_embed(const float* __restrict__ hist,
                const unsigned short* __restrict__ fusedb,
                const float* __restrict__ w_att,
                const float* __restrict__ b_att,
                unsigned short* __restrict__ hembed)
{
    const int lane = threadIdx.x & 63;
    const int wave = threadIdx.x >> 6;
    const int b = blockIdx.x * 4 + wave;
    const int d = lane * 8;

    float g[8];
    {
        u16x8 f = *(const u16x8*)(fusedb + (size_t)b * HIDDEN + d);
        const float4 w0 = *(const float4*)(w_att + d);
        const float4 w1 = *(const float4*)(w_att + d + 4);
        g[0]=bf2f(f[0])*w0.x; g[1]=bf2f(f[1])*w0.y; g[2]=bf2f(f[2])*w0.z; g[3]=bf2f(f[3])*w0.w;
        g[4]=bf2f(f[4])*w1.x; g[5]=bf2f(f[5])*w1.y; g[6]=bf2f(f[6])*w1.z; g[7]=bf2f(f[7])*w1.w;
    }
    const float* hb = hist + (size_t)b * RNDS * HIDDEN + d;

    float h[RNDS][8], p[RNDS];
    #pragma unroll
    for (int r = 0; r < RNDS; ++r) {
        const float4 a0 = *(const float4*)(hb + r * HIDDEN);
        const float4 a1 = *(const float4*)(hb + r * HIDDEN + 4);
        h[r][0]=a0.x; h[r][1]=a0.y; h[r][2]=a0.z; h[r][3]=a0.w;
        h[r][4]=a1.x; h[r][5]=a1.y; h[r][6]=a1.z; h[r][7]=a1.w;
        float s = 0.f;
        #pragma unroll
        for (int i = 0; i < 8; ++i) s += h[r][i] * g[i];
        p[r] = s;
    }
    #pragma unroll
    for (int r = 0; r < RNDS; ++r)
        #pragma unroll
        for (int m = 1; m < 64; m <<= 1)
            p[r] += __shfl_xor(p[r], m, 64);

    const float ba = b_att[0];
    float mx = -1e30f;
    #pragma unroll
    for (int r = 0; r < RNDS; ++r) mx = fmaxf(mx, p[r] + ba);
    float sum = 0.f, a[RNDS];
    #pragma unroll
    for (int r = 0; r < RNDS; ++r) { a[r] = __expf(p[r] + ba - mx); sum += a[r]; }
    const float inv = 1.0f / sum;

    float e[8] = {};
    #pragma unroll
    for (int r = 0; r < RNDS; ++r)
        #pragma unroll
        for (int i = 0; i < 8; ++i) e[i] += a[r] * h[r][i];

    ushort4 o0, o1;
    o0.x=f2bf(e[0]*inv); o0.y=f2bf(e[1]*inv); o0.z=f2bf(e[2]*inv); o0.w=f2bf(e[3]*inv);
    o1.x=f2bf(e[4]*inv); o1.y=f2bf(e[5]*inv); o1.z=f2bf(e[6]*inv); o1.w=f2bf(e[7]*inv);
    unsigned short* q = hembed + (size_t)b * HIDDEN + d;
    *(ushort4*)q = o0;
    *(ushort4*)(q + 4) = o1;
}

extern "C" void kernel_launch(void* const* d_in, const int* in_sizes, int n_in,
                              void* d_out, int out_size, void* d_ws, size_t ws_size,
                              hipStream_t stream)
{
    const float* img    = (const float*)d_in[0];
    const float* ques   = (const float*)d_in[1];
    const float* hist   = (const float*)d_in[2];
    const float* W_fuse = (const float*)d_in[3];
    const float* b_fuse = (const float*)d_in[4];
    const float* w_att  = (const float*)d_in[5];
    const float* b_att  = (const float*)d_in[6];
    const float* W_hist = (const float*)d_in[7];
    const float* b_hist = (const float*)d_in[8];

    const long n_img  = in_sizes[0];
    const long n_ques = in_sizes[1];
    const long n_Wf   = in_sizes[3];
    const long n_Wh   = in_sizes[7];
    const int  BR     = (int)(n_ques / HIDDEN);   // 5120

    unsigned short* imgb   = (unsigned short*)d_ws;
    unsigned short* quesb  = imgb   + n_img;
    unsigned short* Wfb    = quesb  + n_ques;
    unsigned short* Whb    = Wfb    + n_Wf;
    unsigned short* fusedb = Whb    + n_Wh;        // BR*512 bf16
    unsigned short* hembb  = fusedb + (size_t)BR * HIDDEN;

    // 1) fp32 -> bf16 conversions (img, ques, W_fuse, W_hist)
    const long total4 = (n_img + n_ques + n_Wf + n_Wh) / 4;
    cvt_bf16<<<dim3((unsigned)((total4 + 255) / 256)), dim3(256), 0, stream>>>(
        img, n_img, ques, n_ques, W_fuse, n_Wf, W_hist, n_Wh,
        imgb, quesb, Wfb, Whb);

    dim3 blk(256);
    dim3 g1(BR / 32, HIDDEN / 64);   // 160 x 8 = 1280 blocks

    // 2) fusedb = tanh(cat(img,ques) @ W_fuse^T + b_fuse)   (bf16)
    gemm_bt_tanh<false><<<g1, blk, 0, stream>>>(
        imgb, IMGF, quesb, HIDDEN, IMGF,
        Wfb, b_fuse, nullptr, nullptr, fusedb, IMGF + HIDDEN);

    // 3) attention + weighted history sum -> hembb (bf16)
    attn_embed<<<dim3(BR / 4), blk, 0, stream>>>(hist, fusedb, w_att, b_att, hembb);

    // 4) out = fused + tanh(hembb @ W_hist^T + b_hist)
    gemm_bt_tanh<true><<<g1, blk, 0, stream>>>(
        hembb, HIDDEN, nullptr, 0, HIDDEN,
        Whb, b_hist, fusedb, (float*)d_out, nullptr, HIDDEN);
}